// Round 12
// baseline (316.248 us; speedup 1.0000x reference)
//
#include <hip/hip_runtime.h>

// B=131072, T=16, D=2, H=64. 16 rows/wave, 4 waves/block.
// R17 = R7 source verbatim with launch_bounds (256,3) -> (256,1).
// SESSION KEY RULE (confirmed R16): arch-VGPR cap = 512/(2*min_waves) -- the
// backend silently reserves half the budget for the AGPR class. R7's packed
// f32x2 math needed ~110-130 arch regs vs cap 85 -> spill (FETCH 1.9GB) that
// was misattributed to SROA/rule-#20. R16 at (256,1): VGPR 116, zero scratch.
// R17 unlocks the banked win: v_pk_{fma,add,mul}_f32 packed gate math
// (~224 -> ~130 full-rate issues/wave-step), numerics R7-proven (absmax .0625).
#define BSZ 131072
#define TT  16
#define RPB 64
#define BLK 256

#define NEG_LOG2E  (-1.4426950408889634f)
#define TWO_LOG2E  2.8853900817779268f

typedef __bf16 bf16x8 __attribute__((ext_vector_type(8)));
typedef float  f32x4  __attribute__((ext_vector_type(4)));
typedef float  f32x2  __attribute__((ext_vector_type(2)));

#define MFMA(a,b,c) __builtin_amdgcn_mfma_f32_16x16x32_bf16((a),(b),(c),0,0,0)

static __device__ __forceinline__ f32x2 lo2(f32x4 v){ return __builtin_shufflevector(v, v, 0, 1); }
static __device__ __forceinline__ f32x2 hi2(f32x4 v){ return __builtin_shufflevector(v, v, 2, 3); }

__global__ __launch_bounds__(BLK, 1) void flow17(
    const float* __restrict__ x,     // (B,16,2)
    const float* __restrict__ z,     // (B,64)
    const float* __restrict__ W_ih,  // (192,2)
    const float* __restrict__ W_hh,  // (192,64)
    const float* __restrict__ b_ih,  // (192)
    const float* __restrict__ b_hh,  // (192)
    const float* __restrict__ W1,    // (64,32)
    const float* __restrict__ b1,    // (32)
    const float* __restrict__ W2,    // (32,4)
    const float* __restrict__ b2,    // (4)
    float* __restrict__ y_out,       // (B,16,2)
    float* __restrict__ lad_out)     // (B)
{
  // LDS: 16384 + 4096 + 3072 + 2048 + 9216 + 5120 + 512 = 40448 B
  __shared__ __align__(16) __bf16 whhtab[16*64*8];  // z/n-gate B-frags (pre-scaled)
  __shared__ __align__(16) __bf16 w1tab[4*64*8];    // W1 B-frags
  __shared__ __align__(16) f32x4  giA[192];         // {w0,w0,w1,w1} pre-scaled
  __shared__ __align__(16) f32x4  giB[128];         // {br,br,bz,bz},{bn,bn,0,0}
  __shared__ __align__(16) __bf16 hbuf[RPB*72];     // h bf16, stride 72
  __shared__ __align__(16) __bf16 hidbuf[RPB*40];   // hidden, cols 32..39 = ls pad
  __shared__ __align__(16) float  yst[128];         // y_{t-1} [comp][row]

  const int tid  = threadIdx.x;
  const int lane = tid & 63, wave = tid >> 6;
  const int quad = lane >> 4, n16 = lane & 15;
  const int gb   = blockIdx.x * RPB;
  const f32x4 zero = {0.f,0.f,0.f,0.f};

  // ---------- one-time staging ----------
  if (tid < 192) {  // giA: pre-scaled, pre-splatted pairs
    const int j = tid;
    const float sc = (j < 128) ? NEG_LOG2E : TWO_LOG2E;
    const float w0 = W_ih[2*j]*sc, w1 = W_ih[2*j+1]*sc;
    giA[j] = (f32x4){w0, w0, w1, w1};
  }
  if (tid < 64) {   // giB: bias pairs (r,z fold b_ih+b_hh; n only b_ih -- b_hh_n in cninit)
    const float br = (b_ih[tid]      + b_hh[tid]     ) * NEG_LOG2E;
    const float bz = (b_ih[64 + tid] + b_hh[64 + tid]) * NEG_LOG2E;
    const float bn =  b_ih[128 + tid]                  * TWO_LOG2E;
    giB[tid*2]     = (f32x4){br, br, bz, bz};
    giB[tid*2 + 1] = (f32x4){bn, bn, 0.f, 0.f};
  }
  // whhtab: f = (gate-1)*8 + g*2 + kt, gate 1=z (x -log2e), 2=n (x 2log2e)
  #pragma unroll
  for (int i = 0; i < 4; ++i) {
    const int f = i*4 + wave;
    const int gate = 1 + (f >> 3), g = (f >> 1) & 3, kt = f & 1;
    const float sc = (gate == 1) ? NEG_LOG2E : TWO_LOG2E;
    const float* p = W_hh + (size_t)((gate*4 + g)*16 + n16)*64 + kt*32 + quad*8;
    bf16x8 v;
    #pragma unroll
    for (int j = 0; j < 8; ++j) v[j] = (__bf16)(p[j]*sc);
    *(bf16x8*)&whhtab[(f*64 + lane)*8] = v;
  }
  { // w1tab: frag f = c2*2+kt, one per wave (unscaled)
    const int f = wave, c2 = f >> 1, kt = f & 1;
    bf16x8 v;
    #pragma unroll
    for (int j = 0; j < 8; ++j)
      v[j] = (__bf16)W1[(size_t)(kt*32 + quad*8 + j)*32 + c2*16 + n16];
    *(bf16x8*)&w1tab[(f*64 + lane)*8] = v;
  }
  if (tid < 128) yst[tid] = 0.f;
  #pragma unroll
  for (int r4 = 0; r4 < 4; ++r4) {  // z -> hbuf (bf16)
    const int row = (tid >> 4) + r4*16, col = (tid & 15)*4;
    const float4 zv = *(const float4*)&z[(size_t)(gb + row)*64 + col];
    hbuf[row*72 + col+0] = (__bf16)zv.x; hbuf[row*72 + col+1] = (__bf16)zv.y;
    hbuf[row*72 + col+2] = (__bf16)zv.z; hbuf[row*72 + col+3] = (__bf16)zv.w;
  }

  // r-gate B-frags in regs (pre-scaled by -log2e): 32 VGPR
  bf16x8 Whr[4][2];
  #pragma unroll
  for (int g = 0; g < 4; ++g)
    #pragma unroll
    for (int kt = 0; kt < 2; ++kt) {
      const float* p = W_hh + (size_t)(g*16 + n16)*64 + kt*32 + quad*8;
      bf16x8 v;
      #pragma unroll
      for (int j = 0; j < 8; ++j) v[j] = (__bf16)(p[j]*NEG_LOG2E);
      Whr[g][kt] = v;
    }
  bf16x8 W2f;
  #pragma unroll
  for (int j = 0; j < 8; ++j)
    W2f[j] = (n16 < 4) ? (__bf16)W2[(size_t)(quad*8 + j)*4 + n16] : (__bf16)0.f;

  // h state fp32 C-layout: hst[g][i] = h[quad*4+i][g*16+n16]
  f32x4 hst[4];
  #pragma unroll
  for (int g = 0; g < 4; ++g)
    #pragma unroll
    for (int i = 0; i < 4; ++i)
      hst[g][i] = z[(size_t)(gb + wave*16 + quad*4 + i)*64 + g*16 + n16];
  float bhn[4];   // b_hh n-part, scaled (folded into cn C-init)
  #pragma unroll
  for (int g = 0; g < 4; ++g) bhn[g] = b_hh[128 + g*16 + n16]*TWO_LOG2E;
  const float b1v0 = b1[n16], b1v1 = b1[16 + n16];
  const float b2ln = (n16 < 4) ? b2[n16] : 0.f;

  __syncthreads();  // only barrier

  const int arow = wave*16 + n16;
  bf16x8 a0 = *(const bf16x8*)&hbuf[arow*72 + quad*8];
  bf16x8 a1 = *(const bf16x8*)&hbuf[arow*72 + 32 + quad*8];

  const int erow = wave*16 + (lane & 15);
  const int comp = (lane >> 4) & 1;
  const int wrow = wave*16 + quad*4;
  const float* xp = x + (size_t)(gb + erow)*(TT*2) + comp;
  float*       yp = y_out + (size_t)(gb + erow)*(TT*2) + comp;
  float yc = 0.f, prodS = 1.0f;

  #pragma unroll 1
  for (int t = 0; t < TT; ++t) {
    const float xt = (lane < 32) ? xp[t*2] : 0.f;   // issue global load early
    const f32x2 ys0a = *(const f32x2*)&yst[wrow];        // y0 rows (0,1)
    const f32x2 ys0b = *(const f32x2*)&yst[wrow + 2];    // y0 rows (2,3)
    const f32x2 ys1a = *(const f32x2*)&yst[64 + wrow];   // y1 rows (0,1)
    const f32x2 ys1b = *(const f32x2*)&yst[64 + wrow + 2];

    // ---- GRU per col-group g (scaled domain; all packable math as f32x2) ----
    #pragma unroll
    for (int g = 0; g < 4; ++g) {
      const bf16x8 bz0 = *(const bf16x8*)&whhtab[((g*2    )*64 + lane)*8];
      const bf16x8 bz1 = *(const bf16x8*)&whhtab[((g*2 + 1)*64 + lane)*8];
      const bf16x8 bn0 = *(const bf16x8*)&whhtab[((8 + g*2    )*64 + lane)*8];
      const bf16x8 bn1 = *(const bf16x8*)&whhtab[((8 + g*2 + 1)*64 + lane)*8];
      f32x4 cr = MFMA(a0, Whr[g][0], zero); cr = MFMA(a1, Whr[g][1], cr);
      f32x4 cz = MFMA(a0, bz0, zero);       cz = MFMA(a1, bz1, cz);
      const f32x4 cninit = {bhn[g], bhn[g], bhn[g], bhn[g]};
      f32x4 cn = MFMA(a0, bn0, cninit);     cn = MFMA(a1, bn1, cn);

      const f32x4 Ar  = giA[      g*16 + n16];
      const f32x4 Az  = giA[ 64 + g*16 + n16];
      const f32x4 An  = giA[128 + g*16 + n16];
      const f32x4 Bz4 = giB[(g*16 + n16)*2];
      const f32x2 bnp = *(const f32x2*)&giB[(g*16 + n16)*2 + 1];

      #pragma unroll
      for (int m = 0; m < 2; ++m) {
        const f32x2 ys0p = m ? ys0b : ys0a;
        const f32x2 ys1p = m ? ys1b : ys1a;
        const f32x2 crp = m ? hi2(cr) : lo2(cr);
        const f32x2 czp = m ? hi2(cz) : lo2(cz);
        const f32x2 cnp = m ? hi2(cn) : lo2(cn);
        const f32x2 hp  = m ? hi2(hst[g]) : lo2(hst[g]);

        // pre-activations (scaled): sr,sz = -log2e*v; pre = 2log2e*vn
        const f32x2 srp  = lo2(Ar)*ys0p + (hi2(Ar)*ys1p + (crp + lo2(Bz4)));
        const f32x2 szp  = lo2(Az)*ys0p + (hi2(Az)*ys1p + (czp + hi2(Bz4)));
        const f32x2 ginp = lo2(An)*ys0p + (hi2(An)*ys1p + bnp);

        const f32x2 Erp = {__builtin_amdgcn_exp2f(srp.x), __builtin_amdgcn_exp2f(srp.y)};
        const f32x2 drp = Erp + 1.0f;
        const f32x2 rp  = {__builtin_amdgcn_rcpf(drp.x), __builtin_amdgcn_rcpf(drp.y)};
        const f32x2 prep = rp*cnp + ginp;
        // fused tail: hv = [h*S + Ez*(S-2)] / [S*(1+Ez)], S = 1+En
        const f32x2 Ezp = {__builtin_amdgcn_exp2f(fminf(szp.x, 61.f)),
                           __builtin_amdgcn_exp2f(fminf(szp.y, 61.f))};
        const f32x2 Enp = {__builtin_amdgcn_exp2f(fminf(prep.x, 61.f)),
                           __builtin_amdgcn_exp2f(fminf(prep.y, 61.f))};
        const f32x2 Sp   = Enp + 1.0f;
        const f32x2 hpep = hp + Ezp;
        const f32x2 m2ep = Ezp * -2.0f;
        const f32x2 nump = Sp*hpep + m2ep;
        const f32x2 denp = Sp*Ezp + Sp;
        const f32x2 rdp  = {__builtin_amdgcn_rcpf(denp.x), __builtin_amdgcn_rcpf(denp.y)};
        const f32x2 hvp  = nump * rdp;

        hst[g][2*m]   = hvp.x;
        hst[g][2*m+1] = hvp.y;
        hbuf[(wrow + 2*m    )*72 + g*16 + n16] = (__bf16)hvp.x;
        hbuf[(wrow + 2*m + 1)*72 + g*16 + n16] = (__bf16)hvp.y;
      }
    }

    a0 = *(const bf16x8*)&hbuf[arow*72 + quad*8];
    a1 = *(const bf16x8*)&hbuf[arow*72 + 32 + quad*8];

    // ---- MLP1 ----
    #pragma unroll
    for (int c2 = 0; c2 < 2; ++c2) {
      const float bb = c2 ? b1v1 : b1v0;
      const f32x4 binit = {bb, bb, bb, bb};
      f32x4 hc = MFMA(a0, *(const bf16x8*)&w1tab[((c2*2  )*64 + lane)*8], binit);
      hc       = MFMA(a1, *(const bf16x8*)&w1tab[((c2*2+1)*64 + lane)*8], hc);
      #pragma unroll
      for (int i = 0; i < 4; ++i)
        hidbuf[(wrow + i)*40 + c2*16 + n16] = (__bf16)fmaxf(hc[i], 0.f);
    }

    // ---- MLP2: ls -> hidbuf pad (cols 32..39 as 4 floats) ----
    {
      const bf16x8 ha = *(const bf16x8*)&hidbuf[arow*40 + quad*8];
      const f32x4 b2init = {b2ln, b2ln, b2ln, b2ln};
      const f32x4 ls = MFMA(ha, W2f, b2init);
      if (n16 < 4) {
        #pragma unroll
        for (int i = 0; i < 4; ++i)
          ((float*)&hidbuf[(wrow + i)*40 + 32])[n16] = ls[i];
      }
    }

    // ---- epilogue (32 lanes): y update + scale product (log deferred) ----
    if (lane < 32) {
      const float* lsp = (const float*)&hidbuf[erow*40 + 32];
      const float lc = lsp[comp];
      const float l2 = lsp[2 + comp];
      const float s  = __logf(1.0f + __expf(l2)) + 0.001f;
      yc += lc + s * xt;
      prodS *= s;
      yst[comp*64 + erow] = yc;
      yp[t*2] = yc;
    }
  }

  // logabsdet = log(prod_t s_t) per comp, summed over comps (matches reference)
  const float ll  = __logf(prodS);
  const float llo = __shfl(ll, lane ^ 16, 64);
  if (lane < 16) lad_out[gb + wave*16 + lane] = ll + llo;
}

extern "C" void kernel_launch(void* const* d_in, const int* in_sizes, int n_in,
                              void* d_out, int out_size, void* d_ws, size_t ws_size,
                              hipStream_t stream) {
  const float* x    = (const float*)d_in[0];
  const float* z    = (const float*)d_in[1];
  const float* W_ih = (const float*)d_in[2];
  const float* W_hh = (const float*)d_in[3];
  const float* b_ih = (const float*)d_in[4];
  const float* b_hh = (const float*)d_in[5];
  const float* W1   = (const float*)d_in[6];
  const float* b1   = (const float*)d_in[7];
  const float* W2   = (const float*)d_in[8];
  const float* b2   = (const float*)d_in[9];

  float* y_out   = (float*)d_out;
  float* lad_out = y_out + (size_t)BSZ * TT * 2;

  dim3 grid(BSZ / RPB), block(BLK);
  hipLaunchKernelGGL(flow17, grid, block, 0, stream,
                     x, z, W_ih, W_hh, b_ih, b_hh, W1, b1, W2, b2,
                     y_out, lad_out);
}